// Round 10
// baseline (2094.976 us; speedup 1.0000x reference)
//
#include <hip/hip_runtime.h>
#include <hip/hip_bf16.h>
#include <hip/hip_cooperative_groups.h>

namespace cg = cooperative_groups;

// Problem constants
#define B_   64
#define T_   32
#define S_   33      // T+1 LSTM steps
#define V_   32000
#define E_   512
#define H_   1024
#define K_   1536    // E + H

typedef __attribute__((ext_vector_type(8))) short  bf16x8;
typedef __attribute__((ext_vector_type(4))) float  f32x4;

// Split fp32 into hi/lo bf16 pair: x ~= hi + lo  (error ~2^-16 rel)
__device__ inline void split2(float x, unsigned short& hi, unsigned short& lo) {
    __hip_bfloat16 h = __float2bfloat16(x);
    float r = x - __bfloat162float(h);
    __hip_bfloat16 l = __float2bfloat16(r);
    hi = *reinterpret_cast<unsigned short*>(&h);
    lo = *reinterpret_cast<unsigned short*>(&l);
}

__device__ inline f32x4 mfma_bf16(bf16x8 a, bf16x8 b, f32x4 c) {
    return __builtin_amdgcn_mfma_f32_16x16x32_bf16(a, b, c, 0, 0, 0);
}

// ===========================================================================
// PERSISTENT COOPERATIVE KERNEL — prep + all 33 LSTM steps in one dispatch.
// grid 256 blocks (1/CU) x 256 threads (4 waves).
// Block blk owns j-columns {blk*4 .. blk*4+3} for ALL 4 gates
// (gate rows g*1024 + blk*4 + jj -> n-tile of 16 mixed-gate rows).
// Wave w = m-tile (batches 16w..16w+15).  K = 1536 (x-part 512 | h-part 1024).
// c state in registers (thread tid <-> (b = tid>>2, jj = tid&3)).
// h double-buffered hi/lo bf16 in ws; visibility across XCDs via grid.sync().
// ===========================================================================
__global__ __launch_bounds__(256) void lstm_persistent(
    const float* __restrict__ feat, const int* __restrict__ caps,
    const float* __restrict__ Wemb, const float* __restrict__ bemb,
    const float* __restrict__ w_ih, const float* __restrict__ w_hh,
    const float* __restrict__ b_ih, const float* __restrict__ b_hh,
    const float* __restrict__ h0,   const float* __restrict__ c0,
    unsigned short* __restrict__ Whi, unsigned short* __restrict__ Wlo,
    unsigned short* __restrict__ Xhi, unsigned short* __restrict__ Xlo,
    unsigned short* __restrict__ hAhi, unsigned short* __restrict__ hAlo,
    unsigned short* __restrict__ hBhi, unsigned short* __restrict__ hBlo,
    float* __restrict__ out)
{
    cg::grid_group grid = cg::this_grid();
    const int tid = threadIdx.x;
    const int blk = blockIdx.x;
    const int gid = blk * 256 + tid;
    const int gsz = 256 * 256;   // 65536

    // ---- prep 1: split weights into hi/lo bf16, unified [4096][1536] ----
    for (int f = gid; f < 4096 * K_; f += gsz) {
        int row = f / K_;
        int k   = f - row * K_;
        float wv = (k < E_) ? w_ih[(size_t)row * E_ + k]
                            : w_hh[(size_t)row * H_ + (k - E_)];
        unsigned short hi, lo; split2(wv, hi, lo);
        Whi[f] = hi; Wlo[f] = lo;
    }
    // ---- prep 2: build X[t*64+b][e] hi/lo ----
    for (int f = gid; f < 2112 * E_; f += gsz) {
        int e = f & (E_ - 1);
        int row = f >> 9;            // t*64 + b
        int t = row >> 6, b = row & 63;
        float x;
        if (t == 0) x = feat[b * E_ + e];
        else {
            int cap = caps[b * T_ + (t - 1)];
            x = Wemb[(size_t)e * V_ + cap] + bemb[e];
        }
        unsigned short hi, lo; split2(x, hi, lo);
        Xhi[f] = hi; Xlo[f] = lo;
    }
    // ---- prep 3: h0 -> hi/lo buffer A (gsz == 65536 == B_*H_ exactly) ----
    {
        unsigned short hi, lo; split2(h0[gid], hi, lo);
        hAhi[gid] = hi; hAlo[gid] = lo;
    }
    // ---- per-thread persistent state ----
    const int ob = tid >> 2, jj = tid & 3;    // owned (batch, j-offset)
    const int j  = blk * 4 + jj;
    float creg = c0[ob * H_ + j];
    float bias[4];
#pragma unroll
    for (int g = 0; g < 4; ++g) bias[g] = b_ih[g * H_ + j] + b_hh[g * H_ + j];

    const int wave = tid >> 6, lane = tid & 63;
    const int lm = lane & 15, kq8 = (lane >> 4) * 8;
    // B-fragment row lm -> gate row (lm>>2)*1024 + blk*4 + (lm&3)
    const size_t wrow = (size_t)((lm >> 2) * H_ + blk * 4 + (lm & 3)) * K_ + kq8;
    const size_t hrow = (size_t)(wave * 16 + lm) * H_ + kq8;

    __shared__ float gbuf[4][16][16];   // [m-tile wave][batch-in-tile][n]

    grid.sync();   // prep visible to all blocks

    for (int t = 0; t < S_; ++t) {
        const unsigned short* hih = (t & 1) ? hBhi : hAhi;
        const unsigned short* hil = (t & 1) ? hBlo : hAlo;
        unsigned short* hoh = (t & 1) ? hAhi : hBhi;
        unsigned short* hol = (t & 1) ? hAlo : hBlo;

        const size_t xrow = (size_t)(t * 64 + wave * 16 + lm) * E_ + kq8;
        f32x4 acc = f32x4{0.f, 0.f, 0.f, 0.f};

        // x-part: K = 0..511
        for (int kk = 0; kk < E_; kk += 32) {
            bf16x8 bh = *reinterpret_cast<const bf16x8*>(Whi + wrow + kk);
            bf16x8 bl = *reinterpret_cast<const bf16x8*>(Wlo + wrow + kk);
            bf16x8 ah = *reinterpret_cast<const bf16x8*>(Xhi + xrow + kk);
            bf16x8 al = *reinterpret_cast<const bf16x8*>(Xlo + xrow + kk);
            acc = mfma_bf16(ah, bh, acc);
            acc = mfma_bf16(al, bh, acc);
            acc = mfma_bf16(ah, bl, acc);
        }
        // h-part: K = 512..1535
        for (int kk = 0; kk < H_; kk += 32) {
            bf16x8 bh = *reinterpret_cast<const bf16x8*>(Whi + wrow + E_ + kk);
            bf16x8 bl = *reinterpret_cast<const bf16x8*>(Wlo + wrow + E_ + kk);
            bf16x8 ah = *reinterpret_cast<const bf16x8*>(hih + hrow + kk);
            bf16x8 al = *reinterpret_cast<const bf16x8*>(hil + hrow + kk);
            acc = mfma_bf16(ah, bh, acc);
            acc = mfma_bf16(al, bh, acc);
            acc = mfma_bf16(ah, bl, acc);
        }

        // C/D layout (r4-probe-verified): col = lane&15 (n), row = (lane>>4)*4+r (batch)
#pragma unroll
        for (int r = 0; r < 4; ++r) gbuf[wave][(lane >> 4) * 4 + r][lm] = acc[r];
        __syncthreads();

        float gv[4];
#pragma unroll
        for (int g = 0; g < 4; ++g)
            gv[g] = gbuf[ob >> 4][ob & 15][g * 4 + jj] + bias[g];
        float si = 1.f / (1.f + expf(-gv[0]));
        float sf = 1.f / (1.f + expf(-gv[1]));
        float tg = tanhf(gv[2]);
        float so = 1.f / (1.f + expf(-gv[3]));
        creg = sf * creg + si * tg;
        float hn = so * tanhf(creg);
        unsigned short hi, lo; split2(hn, hi, lo);
        hoh[ob * H_ + j] = hi;
        hol[ob * H_ + j] = lo;
        out[((size_t)ob * S_ + t) * H_ + j] = hn;

        grid.sync();   // h visible device-wide; also guards gbuf reuse
    }
}

// ===========================================================================
// FALLBACK PATH — r9 kernels verbatim (proven correct, ~4.9 MB ws).
// ===========================================================================
__device__ inline void load_f32x8_hilo(const float* __restrict__ p,
                                       bf16x8& hi, bf16x8& lo) {
    const float4* q = reinterpret_cast<const float4*>(p);
    float4 v0 = q[0], v1 = q[1];
    float f[8] = {v0.x, v0.y, v0.z, v0.w, v1.x, v1.y, v1.z, v1.w};
#pragma unroll
    for (int jx = 0; jx < 8; ++jx) {
        unsigned short h, l; split2(f[jx], h, l);
        hi[jx] = (short)h; lo[jx] = (short)l;
    }
}

__global__ __launch_bounds__(512) void build_x(
    const float* __restrict__ feat, const int* __restrict__ caps,
    const float* __restrict__ Wemb, const float* __restrict__ bemb,
    unsigned short* __restrict__ Xhi, unsigned short* __restrict__ Xlo)
{
    int row = blockIdx.x;
    int t = row >> 6, b = row & 63;
    int e = threadIdx.x;
    float x;
    if (t == 0) x = feat[b * E_ + e];
    else {
        int cap = caps[b * T_ + (t - 1)];
        x = Wemb[(size_t)e * V_ + cap] + bemb[e];
    }
    unsigned short hi, lo; split2(x, hi, lo);
    Xhi[(size_t)row * E_ + e] = hi;
    Xlo[(size_t)row * E_ + e] = lo;
}

__global__ __launch_bounds__(256) void init_state(
    const float* __restrict__ h0, const float* __restrict__ c0,
    unsigned short* __restrict__ hhi, unsigned short* __restrict__ hlo,
    float* __restrict__ c)
{
    int idx = blockIdx.x * 256 + threadIdx.x;
    unsigned short hi, lo; split2(h0[idx], hi, lo);
    hhi[idx] = hi; hlo[idx] = lo;
    c[idx] = c0[idx];
}

__global__ __launch_bounds__(256) void lstm_step(
    const unsigned short* __restrict__ Xhi, const unsigned short* __restrict__ Xlo,
    const float* __restrict__ w_ih, const float* __restrict__ w_hh,
    const float* __restrict__ b_ih, const float* __restrict__ b_hh,
    const unsigned short* __restrict__ hhi_in, const unsigned short* __restrict__ hlo_in,
    float* __restrict__ c,
    unsigned short* __restrict__ hhi_out, unsigned short* __restrict__ hlo_out,
    float* __restrict__ out, int t)
{
    int bx = blockIdx.x;
    int m0 = (bx & 3) * 16;
    int j0 = (bx >> 2) * 16;
    int wave = threadIdx.x >> 6;
    int lane = threadIdx.x & 63;
    int lm = lane & 15;
    int kq = (lane >> 4) * 8;
    int nrow = wave * H_ + j0 + lm;

    f32x4 acc = f32x4{0.f, 0.f, 0.f, 0.f};
    for (int kk = 0; kk < E_; kk += 32) {
        bf16x8 bhi, blo;
        load_f32x8_hilo(w_ih + (size_t)nrow * E_ + kk + kq, bhi, blo);
        size_t aoff = (size_t)(t * 64 + m0 + lm) * E_ + kk + kq;
        bf16x8 ahi = *reinterpret_cast<const bf16x8*>(Xhi + aoff);
        bf16x8 alo = *reinterpret_cast<const bf16x8*>(Xlo + aoff);
        acc = mfma_bf16(ahi, bhi, acc);
        acc = mfma_bf16(alo, bhi, acc);
        acc = mfma_bf16(ahi, blo, acc);
    }
    for (int kk = 0; kk < H_; kk += 32) {
        bf16x8 bhi, blo;
        load_f32x8_hilo(w_hh + (size_t)nrow * H_ + kk + kq, bhi, blo);
        size_t aoff = (size_t)(m0 + lm) * H_ + kk + kq;
        bf16x8 ahi = *reinterpret_cast<const bf16x8*>(hhi_in + aoff);
        bf16x8 alo = *reinterpret_cast<const bf16x8*>(hlo_in + aoff);
        acc = mfma_bf16(ahi, bhi, acc);
        acc = mfma_bf16(alo, bhi, acc);
        acc = mfma_bf16(ahi, blo, acc);
    }

    __shared__ float gbuf[4][16][16];
    int rbase = (lane >> 4) * 4;
#pragma unroll
    for (int r = 0; r < 4; ++r) gbuf[wave][rbase + r][lm] = acc[r];
    __syncthreads();

    int tid = threadIdx.x;
    int m = tid >> 4, jx = tid & 15;
    int b = m0 + m;
    int jg = j0 + jx;
    float iv = gbuf[0][m][jx] + b_ih[0 * H_ + jg] + b_hh[0 * H_ + jg];
    float fv = gbuf[1][m][jx] + b_ih[1 * H_ + jg] + b_hh[1 * H_ + jg];
    float gvv = gbuf[2][m][jx] + b_ih[2 * H_ + jg] + b_hh[2 * H_ + jg];
    float ov = gbuf[3][m][jx] + b_ih[3 * H_ + jg] + b_hh[3 * H_ + jg];
    float si = 1.f / (1.f + expf(-iv));
    float sf = 1.f / (1.f + expf(-fv));
    float so = 1.f / (1.f + expf(-ov));
    float tg = tanhf(gvv);
    size_t cidx = (size_t)b * H_ + jg;
    float cn = sf * c[cidx] + si * tg;
    c[cidx] = cn;
    float hn = so * tanhf(cn);
    unsigned short hi, lo; split2(hn, hi, lo);
    hhi_out[cidx] = hi;
    hlo_out[cidx] = lo;
    out[((size_t)b * S_ + t) * H_ + jg] = hn;
}

// ---------------------------------------------------------------------------
extern "C" void kernel_launch(void* const* d_in, const int* in_sizes, int n_in,
                              void* d_out, int out_size, void* d_ws, size_t ws_size,
                              hipStream_t stream)
{
    const float* feat = (const float*)d_in[0];
    const int*   caps = (const int*)d_in[1];
    const float* Wemb = (const float*)d_in[2];
    const float* bemb = (const float*)d_in[3];
    const float* w_ih = (const float*)d_in[4];
    const float* w_hh = (const float*)d_in[5];
    const float* b_ih = (const float*)d_in[6];
    const float* b_hh = (const float*)d_in[7];
    const float* h0   = (const float*)d_in[8];
    const float* c0   = (const float*)d_in[9];
    int nbias = 0, nstate = 0;
    for (int i = 0; i < n_in; ++i) {
        switch (in_sizes[i]) {
            case 64 * 512:    feat = (const float*)d_in[i]; break;
            case 64 * 32:     caps = (const int*)d_in[i];   break;
            case 512 * 32000: Wemb = (const float*)d_in[i]; break;
            case 512:         bemb = (const float*)d_in[i]; break;
            case 4096 * 512:  w_ih = (const float*)d_in[i]; break;
            case 4096 * 1024: w_hh = (const float*)d_in[i]; break;
            case 4096:
                if (nbias++ == 0) b_ih = (const float*)d_in[i];
                else              b_hh = (const float*)d_in[i];
                break;
            case 64 * 1024:
                if (nstate++ == 0) h0 = (const float*)d_in[i];
                else               c0 = (const float*)d_in[i];
                break;
            default: break;
        }
    }
    float* out = (float*)d_out;

    // --- persistent-path ws layout (~29.9 MB) ---
    const size_t szW = (size_t)4096 * K_;        // 6.29M ushort = 12.58 MB each
    const size_t szX = (size_t)2112 * E_;        // 1.08M ushort = 2.06 MB each
    const size_t szH = (size_t)B_ * H_;          // 64K ushort = 128 KB each
    const size_t need = (2 * szW + 2 * szX + 4 * szH) * sizeof(unsigned short);

    hipError_t coopErr = hipErrorUnknown;
    if (ws_size >= need) {
        char* ws = (char*)d_ws;
        unsigned short* Whi  = (unsigned short*)ws; ws += szW * 2;
        unsigned short* Wlo  = (unsigned short*)ws; ws += szW * 2;
        unsigned short* Xhi  = (unsigned short*)ws; ws += szX * 2;
        unsigned short* Xlo  = (unsigned short*)ws; ws += szX * 2;
        unsigned short* hAhi = (unsigned short*)ws; ws += szH * 2;
        unsigned short* hAlo = (unsigned short*)ws; ws += szH * 2;
        unsigned short* hBhi = (unsigned short*)ws; ws += szH * 2;
        unsigned short* hBlo = (unsigned short*)ws; ws += szH * 2;

        void* args[] = {
            (void*)&feat, (void*)&caps, (void*)&Wemb, (void*)&bemb,
            (void*)&w_ih, (void*)&w_hh, (void*)&b_ih, (void*)&b_hh,
            (void*)&h0,   (void*)&c0,
            (void*)&Whi,  (void*)&Wlo,  (void*)&Xhi,  (void*)&Xlo,
            (void*)&hAhi, (void*)&hAlo, (void*)&hBhi, (void*)&hBlo,
            (void*)&out
        };
        coopErr = hipLaunchCooperativeKernel((const void*)lstm_persistent,
                                             dim3(256), dim3(256),
                                             args, 0, stream);
    }

    if (coopErr != hipSuccess) {
        // r9 fallback path (~4.9 MB ws, proven)
        char* ws = (char*)d_ws;
        unsigned short* Xhi  = (unsigned short*)ws; ws += szX * 2;
        unsigned short* Xlo  = (unsigned short*)ws; ws += szX * 2;
        unsigned short* hhiA = (unsigned short*)ws; ws += szH * 2;
        unsigned short* hloA = (unsigned short*)ws; ws += szH * 2;
        unsigned short* hhiB = (unsigned short*)ws; ws += szH * 2;
        unsigned short* hloB = (unsigned short*)ws; ws += szH * 2;
        float* cbuf          = (float*)ws;          ws += szH * 4;

        build_x<<<2112, 512, 0, stream>>>(feat, caps, Wemb, bemb, Xhi, Xlo);
        init_state<<<256, 256, 0, stream>>>(h0, c0, hhiA, hloA, cbuf);
        for (int t = 0; t < S_; ++t) {
            const unsigned short* hhi_in = (t & 1) ? hhiB : hhiA;
            const unsigned short* hlo_in = (t & 1) ? hloB : hloA;
            unsigned short* hhi_out = (t & 1) ? hhiA : hhiB;
            unsigned short* hlo_out = (t & 1) ? hloA : hloB;
            lstm_step<<<256, 256, 0, stream>>>(Xhi, Xlo, w_ih, w_hh, b_ih, b_hh,
                                               hhi_in, hlo_in, cbuf,
                                               hhi_out, hlo_out, out, t);
        }
    }
}